// Round 7
// baseline (318.911 us; speedup 1.0000x reference)
//
#include <hip/hip_runtime.h>

typedef unsigned int uint32;
typedef __attribute__((ext_vector_type(8))) short short8v;  // 8 bf16 (4 VGPRs)
typedef __attribute__((ext_vector_type(4))) float f32x4;

__device__ __forceinline__ unsigned short f2bf(float f) {
  unsigned u = __float_as_uint(f);
  return (unsigned short)((u + 0x7FFFu + ((u >> 16) & 1u)) >> 16);
}
__device__ __forceinline__ float bfl(unsigned x) { return __uint_as_float(x << 16); }
__device__ __forceinline__ float bfh(unsigned x) { return __uint_as_float(x & 0xFFFF0000u); }

// Generation-based grid barrier on device-scope (agent) atomics. Requires all
// blocks co-resident: guaranteed by __launch_bounds__(256,2) + grid <= 2*numCU.
// Bounded spin (~0.5s) as a safety valve: wrong answer beats a hung harness.
__device__ __forceinline__ void grid_barrier(int* cnt, int* gen) {
  __syncthreads();
  if (threadIdx.x == 0) {
    __threadfence();  // release: prior global writes visible device-wide
    int g = __hip_atomic_load(gen, __ATOMIC_RELAXED, __HIP_MEMORY_SCOPE_AGENT);
    int arrived = __hip_atomic_fetch_add(cnt, 1, __ATOMIC_ACQ_REL, __HIP_MEMORY_SCOPE_AGENT);
    if (arrived == (int)gridDim.x - 1) {
      __hip_atomic_store(cnt, 0, __ATOMIC_RELAXED, __HIP_MEMORY_SCOPE_AGENT);
      __hip_atomic_fetch_add(gen, 1, __ATOMIC_ACQ_REL, __HIP_MEMORY_SCOPE_AGENT);
    } else {
      int spins = 0;
      while (__hip_atomic_load(gen, __ATOMIC_ACQUIRE, __HIP_MEMORY_SCOPE_AGENT) == g) {
        __builtin_amdgcn_s_sleep(8);
        if (++spins > (1 << 22)) break;
      }
    }
    __threadfence();  // acquire side
  }
  __syncthreads();
}

// P2 helper: one LANE per edge. Coalesced 32B idx + mask loads, 8 scalar sigma
// gathers (L2-resident 400KB table), in-lane softmax, atomicAdd att into W8[n][a].
template <int MSZ>
__device__ __forceinline__ void edge_attend(const int* __restrict__ elist,
                                            const void* __restrict__ maskp,
                                            const float* __restrict__ sigma,
                                            float* __restrict__ W8, int m) {
  const int4 ia = ((const int4*)elist)[m * 2];
  const int4 ib = ((const int4*)elist)[m * 2 + 1];
  const int idx[8] = {ia.x, ia.y, ia.z, ia.w, ib.x, ib.y, ib.z, ib.w};
  int vld[8];
  if (MSZ == 4) {
    const int4 ma = ((const int4*)maskp)[m * 2];
    const int4 mb = ((const int4*)maskp)[m * 2 + 1];
    vld[0] = ma.x; vld[1] = ma.y; vld[2] = ma.z; vld[3] = ma.w;
    vld[4] = mb.x; vld[5] = mb.y; vld[6] = mb.z; vld[7] = mb.w;
  } else {
    const uint2 u = ((const uint2*)maskp)[m];
    vld[0] = u.x & 0xFF; vld[1] = (u.x >> 8) & 0xFF;
    vld[2] = (u.x >> 16) & 0xFF; vld[3] = u.x >> 24;
    vld[4] = u.y & 0xFF; vld[5] = (u.y >> 8) & 0xFF;
    vld[6] = (u.y >> 16) & 0xFF; vld[7] = u.y >> 24;
  }
  float sg[8];
  #pragma unroll
  for (int a = 0; a < 8; ++a) sg[a] = sigma[idx[a]];
  float mx = -3.0e38f;
  #pragma unroll
  for (int a = 0; a < 8; ++a) mx = fmaxf(mx, vld[a] ? sg[a] : -3.0e38f);
  float ev[8];
  float dn = 0.f;
  #pragma unroll
  for (int a = 0; a < 8; ++a) {
    ev[a] = vld[a] ? __expf(sg[a] - mx) : 0.f;
    dn += ev[a];
  }
  const float inv = __fdividef(1.f, dn);
  #pragma unroll
  for (int a = 0; a < 8; ++a)
    if (vld[a]) atomicAdd(&W8[(size_t)idx[a] * 8 + a], ev[a] * inv);
}

__global__ __launch_bounds__(256, 2) void fused_all(
    const float* __restrict__ X, const float* __restrict__ W,
    const float* __restrict__ a1, const int* __restrict__ elist,
    const void* __restrict__ maskp, unsigned short* __restrict__ Wh,
    float* __restrict__ sigma, float* __restrict__ W8,
    int* __restrict__ bar, int* __restrict__ flag,
    float* __restrict__ out, int N, int M) {
  __shared__ short sB[2048 * 8];  // 32 KiB: P1 W-fragments; P3 reuses as reduce buf
  const int tid = threadIdx.x;
  const int gtid = blockIdx.x * 256 + tid;
  const int nthreads = gridDim.x * 256;
  const int lane = tid & 63;
  const int wv = tid >> 6;

  // ---- P0: detect mask element size (1B bool vs 4B). W8/out zeroed by memset nodes. ----
  if (blockIdx.x == 0 && tid < 64) {
    const uint32* md = (const uint32*)maskp;
    bool ok4 = true;
    for (int i = tid; i < 1024; i += 64) {
      uint32 v = md[i];
      if (!(v == 0u || v == 1u || v == 0x3F800000u)) ok4 = false;
    }
    bool all4 = __all(ok4);
    if (tid == 0)
      __hip_atomic_store(flag, all4 ? 4 : 1, __ATOMIC_RELAXED, __HIP_MEMORY_SCOPE_AGENT);
  }

  // ---- P1: Wh = X @ W1 via mfma_f32_16x16x32_bf16, + sigma epilogue ----
  for (int i = tid; i < 2048; i += 256) {
    const int frag = i >> 6, ln = i & 63;
    const int kt = frag >> 3, ct = frag & 7, p = ln >> 4, q = ln & 15;
    short8v v;
    #pragma unroll
    for (int j = 0; j < 8; ++j)
      v[j] = (short)f2bf(W[(kt * 32 + p * 8 + j) * 128 + ct * 16 + q]);
    *(short8v*)&sB[i * 8] = v;
  }
  __syncthreads();
  {
    const int p = lane >> 4, q = lane & 15;
    float a1v[8];
    #pragma unroll
    for (int ct = 0; ct < 8; ++ct) a1v[ct] = a1[ct * 16 + q];
    const int wave = blockIdx.x * 4 + wv;
    const int nwaves = gridDim.x * 4;
    const int nstrips = (N + 15) >> 4;
    for (int s = wave; s < nstrips; s += nwaves) {
      const int row = s * 16 + q;
      const int rclamp = row < N ? row : (N - 1);
      const float* xr = X + (size_t)rclamp * 128 + p * 8;
      float4 L[8];
      #pragma unroll
      for (int kt = 0; kt < 4; ++kt) {
        L[2 * kt]     = *(const float4*)(xr + kt * 32);
        L[2 * kt + 1] = *(const float4*)(xr + kt * 32 + 4);
      }
      short8v A[4];
      #pragma unroll
      for (int kt = 0; kt < 4; ++kt) {
        #pragma unroll
        for (int j = 0; j < 4; ++j) {
          A[kt][j]     = (short)f2bf((&L[2 * kt].x)[j]);
          A[kt][j + 4] = (short)f2bf((&L[2 * kt + 1].x)[j]);
        }
      }
      f32x4 acc[8];
      #pragma unroll
      for (int ct = 0; ct < 8; ++ct) acc[ct] = (f32x4){0.f, 0.f, 0.f, 0.f};
      #pragma unroll
      for (int kt = 0; kt < 4; ++kt) {
        #pragma unroll
        for (int ct = 0; ct < 8; ++ct) {
          short8v b = *(const short8v*)&sB[((kt * 8 + ct) * 64 + lane) * 8];
          acc[ct] = __builtin_amdgcn_mfma_f32_16x16x32_bf16(A[kt], b, acc[ct], 0, 0, 0);
        }
      }
      const int r0 = s * 16 + p * 4;
      #pragma unroll
      for (int ct = 0; ct < 8; ++ct) {
        #pragma unroll
        for (int r = 0; r < 4; ++r) {
          const int rr = r0 + r;
          if (rr < N) Wh[(size_t)rr * 128 + ct * 16 + q] = f2bf(acc[ct][r]);
        }
      }
      #pragma unroll
      for (int r = 0; r < 4; ++r) {
        float tsum = 0.f;
        #pragma unroll
        for (int ct = 0; ct < 8; ++ct) {
          const float v = acc[ct][r];
          tsum += fmaxf(v, 0.2f * v) * a1v[ct];
        }
        tsum += __shfl_xor(tsum, 1);
        tsum += __shfl_xor(tsum, 2);
        tsum += __shfl_xor(tsum, 4);
        tsum += __shfl_xor(tsum, 8);
        const int rr = r0 + r;
        if (q == r && rr < N) sigma[rr] = tsum;
      }
    }
  }

  grid_barrier(bar, bar + 16);

  // ---- P2: per-edge softmax -> W8 atomics (one lane per edge) ----
  {
    const int msz = __hip_atomic_load(flag, __ATOMIC_RELAXED, __HIP_MEMORY_SCOPE_AGENT);
    if (msz == 4) {
      for (int m = gtid; m < M; m += nthreads)
        edge_attend<4>(elist, maskp, sigma, W8, m);
    } else {
      for (int m = gtid; m < M; m += nthreads)
        edge_attend<1>(elist, maskp, sigma, W8, m);
    }
  }

  grid_barrier(bar, bar + 16);

  // ---- P3: out[a][f] += sum_n W8[n][a] * Wh[n][f] (streaming + block reduce) ----
  {
    const uint32* Wh32 = (const uint32*)Wh;
    float* sAcc = (float*)sB;  // [4][1024] = 16 KiB
    const int wave = blockIdx.x * 4 + wv;
    const int nw = gridDim.x * 4;
    float acc[16];
    #pragma unroll
    for (int j = 0; j < 16; ++j) acc[j] = 0.f;

    for (int n = wave; n < N; n += 2 * nw) {
      const int n2 = n + nw;
      const uint32 d0 = Wh32[(size_t)n * 64 + lane];
      const float4 wa0 = *(const float4*)&W8[(size_t)n * 8];
      const float4 wb0 = *(const float4*)&W8[(size_t)n * 8 + 4];
      uint32 d1 = 0;
      float4 wa1 = {0.f, 0.f, 0.f, 0.f}, wb1 = {0.f, 0.f, 0.f, 0.f};
      if (n2 < N) {
        d1 = Wh32[(size_t)n2 * 64 + lane];
        wa1 = *(const float4*)&W8[(size_t)n2 * 8];
        wb1 = *(const float4*)&W8[(size_t)n2 * 8 + 4];
      }
      const float lo0 = bfl(d0), hi0 = bfh(d0);
      acc[0]  = fmaf(wa0.x, lo0, acc[0]);  acc[1]  = fmaf(wa0.x, hi0, acc[1]);
      acc[2]  = fmaf(wa0.y, lo0, acc[2]);  acc[3]  = fmaf(wa0.y, hi0, acc[3]);
      acc[4]  = fmaf(wa0.z, lo0, acc[4]);  acc[5]  = fmaf(wa0.z, hi0, acc[5]);
      acc[6]  = fmaf(wa0.w, lo0, acc[6]);  acc[7]  = fmaf(wa0.w, hi0, acc[7]);
      acc[8]  = fmaf(wb0.x, lo0, acc[8]);  acc[9]  = fmaf(wb0.x, hi0, acc[9]);
      acc[10] = fmaf(wb0.y, lo0, acc[10]); acc[11] = fmaf(wb0.y, hi0, acc[11]);
      acc[12] = fmaf(wb0.z, lo0, acc[12]); acc[13] = fmaf(wb0.z, hi0, acc[13]);
      acc[14] = fmaf(wb0.w, lo0, acc[14]); acc[15] = fmaf(wb0.w, hi0, acc[15]);
      const float lo1 = bfl(d1), hi1 = bfh(d1);
      acc[0]  = fmaf(wa1.x, lo1, acc[0]);  acc[1]  = fmaf(wa1.x, hi1, acc[1]);
      acc[2]  = fmaf(wa1.y, lo1, acc[2]);  acc[3]  = fmaf(wa1.y, hi1, acc[3]);
      acc[4]  = fmaf(wa1.z, lo1, acc[4]);  acc[5]  = fmaf(wa1.z, hi1, acc[5]);
      acc[6]  = fmaf(wa1.w, lo1, acc[6]);  acc[7]  = fmaf(wa1.w, hi1, acc[7]);
      acc[8]  = fmaf(wb1.x, lo1, acc[8]);  acc[9]  = fmaf(wb1.x, hi1, acc[9]);
      acc[10] = fmaf(wb1.y, lo1, acc[10]); acc[11] = fmaf(wb1.y, hi1, acc[11]);
      acc[12] = fmaf(wb1.z, lo1, acc[12]); acc[13] = fmaf(wb1.z, hi1, acc[13]);
      acc[14] = fmaf(wb1.w, lo1, acc[14]); acc[15] = fmaf(wb1.w, hi1, acc[15]);
    }

    __syncthreads();
    #pragma unroll
    for (int a = 0; a < 8; ++a) {
      sAcc[wv * 1024 + a * 128 + 2 * lane]     = acc[2 * a];
      sAcc[wv * 1024 + a * 128 + 2 * lane + 1] = acc[2 * a + 1];
    }
    __syncthreads();
    const int c = tid * 4;
    float4 s = {0.f, 0.f, 0.f, 0.f};
    #pragma unroll
    for (int w = 0; w < 4; ++w) {
      const float4 v = *(const float4*)&sAcc[w * 1024 + c];
      s.x += v.x; s.y += v.y; s.z += v.z; s.w += v.w;
    }
    atomicAdd(&out[c], s.x);
    atomicAdd(&out[c + 1], s.y);
    atomicAdd(&out[c + 2], s.z);
    atomicAdd(&out[c + 3], s.w);
  }
}

extern "C" void kernel_launch(void* const* d_in, const int* in_sizes, int n_in,
                              void* d_out, int out_size, void* d_ws, size_t ws_size,
                              hipStream_t stream) {
  const float* node  = (const float*)d_in[0];
  const int* elist   = (const int*)d_in[2];
  const void* maskp  = (const void*)d_in[3];
  const float* W1    = (const float*)d_in[4];
  const float* a1    = (const float*)d_in[5];
  float* out         = (float*)d_out;

  int N = in_sizes[0] / 128;
  int M = in_sizes[2] / 8;

  char* ws = (char*)d_ws;
  unsigned short* Wh = (unsigned short*)ws;              // N*256 B
  size_t off = (size_t)N * 256;
  float* sigma = (float*)(ws + off);  off += (size_t)N * 4;
  off = (off + 255) & ~(size_t)255;
  float* W8 = (float*)(ws + off);
  const size_t zeroBytes = (size_t)N * 32 + 256;         // W8 + barrier state + flag
  int* bar  = (int*)(ws + off + (size_t)N * 32);         // [cnt, ..., gen at +16]
  int* flag = bar + 32;
  off += zeroBytes;

  int dev = 0;
  (void)hipGetDevice(&dev);
  int cu = 0;
  (void)hipDeviceGetAttribute(&cu, hipDeviceAttributeMultiprocessorCount, dev);
  if (cu <= 0) cu = 256;
  int grid = 2 * cu;                 // co-resident per __launch_bounds__(256,2)
  if (grid > 512) grid = 512;

  (void)hipMemsetAsync(W8, 0, zeroBytes, stream);              // W8 + bar + flag = 0
  (void)hipMemsetAsync(out, 0, (size_t)out_size * 4, stream);  // out = 0 (P3 atomics)
  fused_all<<<grid, 256, 0, stream>>>(node, W1, a1, elist, maskp, Wh, sigma, W8,
                                      bar, flag, out, N, M);
}